// Round 8
// baseline (2731.630 us; speedup 1.0000x reference)
//
#include <hip/hip_runtime.h>
#include <stdint.h>

// LSTM(relu) persistent kernel v8: B=64,S=1024,F=128,H=512.
// v7 structure (XCD-local groups via HW_REG_XCC_ID, fence-free L2 sync,
// LDS-resident [U;W]^T, 4-wave K-split, per-tile epilogue) with the CU-level
// sync protocol dissolved into a PER-WAVE protocol:
//  - producer wave w publishes its own flag after draining its own h-store
//    (no barrier3, no CU-wide vmcnt convoy)
//  - consumer wave w polls ONLY its 32 dependency flags (slots 8w..8w+7 x
//    4 waves) -> no barrier1, stragglers absorbed per-wave
//  - ONE __syncthreads per step (partial-reduce); R double-buffered so the
//    reuse race closes via: readers(t) -> their flags(t+1) -> every CU's
//    4 waves jointly poll all 32 slots -> barrier(t+1) -> writers(t+2).
// 256 wgs x 256 thr, ~115KB LDS -> exactly 1 wg/CU (XCD pigeonhole intact).

#define S_ 1024
#define F_ 128
#define H_ 512
#define G4_ 2048
#define SLOTS 32        // wgs per XCD group
#define KH 16           // h@U K-steps (512/32)
#define LDKS 640        // shorts per LDS weight row (k dim)
#define HB (64 * H_)    // one h buffer: 64 rows x 512 units

typedef __attribute__((ext_vector_type(8))) short short8;  // 8 x bf16
typedef __attribute__((ext_vector_type(4))) float f32x4;
typedef unsigned long long ull;

__device__ __forceinline__ unsigned short f2bf(float f) {
  union { float f; unsigned u; } v; v.f = f;
  unsigned u = v.u + 0x7fffu + ((v.u >> 16) & 1u);   // RNE
  return (unsigned short)(u >> 16);
}

__device__ __forceinline__ short8 pack2(f32x4 a, f32x4 b) {
  short8 r;
#pragma unroll
  for (int i = 0; i < 4; ++i) r[i] = (short)f2bf(a[i]);
#pragma unroll
  for (int i = 0; i < 4; ++i) r[4 + i] = (short)f2bf(b[i]);
  return r;
}

// swizzled short-index into V (validated in v5/v6/v7)
__device__ __forceinline__ int swz(int cc, int k) {
  return (cc * LDKS + k) ^ ((cc & 7) << 3);
}

__global__ __launch_bounds__(256, 1) void lstm_pers(
    const float* __restrict__ x, const float* __restrict__ W,
    const float* __restrict__ U, const float* __restrict__ bias,
    float* __restrict__ out, unsigned int* ws_sync, unsigned short* hbuf) {

  __shared__ unsigned short V[64 * LDKS];   // 81920 B
  __shared__ f32x4 R[2][4][4][64];          // 32768 B partial staging (dbuf)
  __shared__ int meta[2];

  const int tid  = threadIdx.x;
  const int w    = tid >> 6;           // wave 0..3 (owns tile w; k-steps 4w..4w+3)
  const int lane = tid & 63;
  const int l15  = lane & 15;
  const int l4   = lane >> 4;
  const int koff = l4 * 8;

  // ---- physical XCD id + slot claim (robust group formation) ----
  if (tid == 0) {
    unsigned int xcc;
    asm volatile("s_getreg_b32 %0, hwreg(20, 0, 4)" : "=s"(xcc));  // HW_REG_XCC_ID
    xcc &= 7;
    unsigned sv = atomicAdd(ws_sync + xcc * 32, 1u);   // 128B-spaced ctrs
    meta[0] = (int)xcc;
    meta[1] = (int)(sv & 31);
  }
  __syncthreads();
  const int xcc  = meta[0];
  const int slot = meta[1];

  // flags: per group, 128 uints (slot*4 + wave), 512B, line-packed
  unsigned int* gflags = ws_sync + 256 + xcc * 128;
  unsigned int* myflag = gflags + slot * 4 + w;
  unsigned int* pollp  = gflags + 32 * w + (lane & 31);  // my 8 slots x 4 waves

  const int u0    = slot * 16;       // 16 units per wg
  const int bbase = xcc * 8;         // 8 batch rows per group

  // ---- LDS fill (identical decomposition to v5/v6/v7) ----
  for (int idx = tid; idx < (64 * LDKS) / 4; idx += 256) {
    const int q4   = idx & 15;
    const int k    = idx >> 4;                // 0..639
    const int gate = q4 & 3;
    const int ul0  = (q4 >> 2) * 4;           // 0,4,8,12
    const int col  = gate * H_ + u0 + ul0;
    const float* src = (k < H_) ? (U + (size_t)k * G4_ + col)
                                : (W + (size_t)(k - H_) * G4_ + col);
    const f32x4 v4 = *(const f32x4*)src;
#pragma unroll
    for (int q = 0; q < 4; ++q) {
      const int ul = ul0 + q;
      const int cc = (ul >> 2) * 16 + (ul & 3) * 4 + gate;
      V[swz(cc, k)] = f2bf(v4[q]);
    }
  }

  // wave w's gate bias for tile w: unit = u0 + w*4 + l4
  float bias_r[4];
#pragma unroll
  for (int g = 0; g < 4; ++g) bias_r[g] = bias[g * H_ + u0 + w * 4 + l4];

  __syncthreads();

  const int brow = bbase + (l15 & 7);   // rows duplicated for l15>=8
  const float* xrow = x + (size_t)brow * S_ * F_ + koff + w * 32;
  const unsigned short* hrow0 = hbuf + (size_t)brow * H_ + koff;
  const int myunit = u0 + w * 4 + l4;   // this lane's (row,unit) in tile w

  float cst = 0.f;                      // c-state of (brow, myunit)

  // preload x(0) slice for this wave
  f32x4 xa = *(const f32x4*)(xrow);
  f32x4 xb = *(const f32x4*)(xrow + 4);

  for (int t = 0; t < S_; ++t) {
    // ---- x @ W first (h-independent): hides poll + flag latency below ----
    f32x4 acc[4];
#pragma unroll
    for (int tl = 0; tl < 4; ++tl) { acc[tl][0]=0.f; acc[tl][1]=0.f; acc[tl][2]=0.f; acc[tl][3]=0.f; }
    {
      const short8 bx = pack2(xa, xb);
      const int k0 = (KH + w) * 32 + koff;
#pragma unroll
      for (int tl = 0; tl < 4; ++tl) {
        const short8 a = *(const short8*)&V[swz(tl * 16 + l15, k0)];
        acc[tl] = __builtin_amdgcn_mfma_f32_16x16x32_bf16(a, bx, acc[tl], 0, 0, 0);
      }
    }

    // ---- issue x(t+1) loads now; they complete under h@U ----
    {
      const int tn = (t + 1 < S_) ? t + 1 : t;
      const float* xt = xrow + (size_t)tn * F_;
      xa = *(const f32x4*)(xt);
      xb = *(const f32x4*)(xt + 4);
    }

    // ---- per-wave poll of MY 32 dependency flags (1 coalesced line) ----
    if (t > 0) {
      const unsigned tgt = (unsigned)t;
      while (true) {
        unsigned v = __hip_atomic_load(pollp, __ATOMIC_RELAXED, __HIP_MEMORY_SCOPE_AGENT);
        if (__all((int)(v >= tgt))) break;
      }
      asm volatile("" ::: "memory");   // keep h loads below the poll

      // ---- my h B-frags (k-steps 4w..4w+3) + h@U ----
      const unsigned short* hr = hrow0 + (size_t)(t & 1) * HB;
      short8 bh[4];
#pragma unroll
      for (int i = 0; i < 4; ++i) {
        union { ull u[2]; short8 s; } bb;
        const ull* hq = (const ull*)(hr + (4 * w + i) * 32);
        bb.u[0] = __hip_atomic_load(hq,     __ATOMIC_RELAXED, __HIP_MEMORY_SCOPE_AGENT);
        bb.u[1] = __hip_atomic_load(hq + 1, __ATOMIC_RELAXED, __HIP_MEMORY_SCOPE_AGENT);
        bh[i] = bb.s;
      }
#pragma unroll
      for (int i = 0; i < 4; ++i) {
        const int k0 = (4 * w + i) * 32 + koff;
#pragma unroll
        for (int tl = 0; tl < 4; ++tl) {
          const short8 a = *(const short8*)&V[swz(tl * 16 + l15, k0)];
          acc[tl] = __builtin_amdgcn_mfma_f32_16x16x32_bf16(a, bh[i], acc[tl], 0, 0, 0);
        }
      }
    }

    // ---- stage partials (double-buffered); ONE barrier per step ----
    const int p = t & 1;
#pragma unroll
    for (int tl = 0; tl < 4; ++tl) R[p][w][tl][lane] = acc[tl];
    __syncthreads();
    // R[p] reuse at t+2 is safe: readers(t) set flags(t+1) after reading;
    // every CU's 4 waves jointly poll all 32 slots at t+1, then pass this
    // barrier at t+1, and only then can any wave write R[p] at t+2.

    // ---- wave w reduces ITS tile; gates; publish own slice ----
    f32x4 z;
    {
      const f32x4 r0 = R[p][0][w][lane], r1 = R[p][1][w][lane],
                  r2 = R[p][2][w][lane], r3 = R[p][3][w][lane];
#pragma unroll
      for (int g = 0; g < 4; ++g)
        z[g] = bias_r[g] + r0[g] + r1[g] + r2[g] + r3[g];
    }

    const float ig = 1.f / (1.f + __expf(-z[0]));
    const float fg = 1.f / (1.f + __expf(-z[1]));
    const float gg = fmaxf(z[2], 0.f);             // relu candidate
    const float og = 1.f / (1.f + __expf(-z[3]));
    const float cn = fg * cst + ig * gg;
    cst = cn;
    const float hv = og * fmaxf(cn, 0.f);          // relu output activation

    if (l15 < 8)
      hbuf[(size_t)((t + 1) & 1) * HB + (size_t)brow * H_ + myunit] = f2bf(hv);
    asm volatile("s_waitcnt vmcnt(0)" ::: "memory");   // MY h slice at L2
    if (lane == 0)
      __hip_atomic_store(myflag, (unsigned)(t + 1), __ATOMIC_RELAXED, __HIP_MEMORY_SCOPE_AGENT);
    if (l15 < 8)
      out[((size_t)brow * S_ + t) * H_ + myunit] = hv;   // off the publish path
  }
}

extern "C" void kernel_launch(void* const* d_in, const int* in_sizes, int n_in,
                              void* d_out, int out_size, void* d_ws, size_t ws_size,
                              hipStream_t stream) {
  const float* x = (const float*)d_in[0];
  const float* W = (const float*)d_in[1];
  const float* U = (const float*)d_in[2];
  const float* b = (const float*)d_in[3];
  float* out = (float*)d_out;

  unsigned int*   ws_sync = (unsigned int*)d_ws;                    // ctrs(1KB) + flags(4KB)
  unsigned short* hbuf    = (unsigned short*)((char*)d_ws + 32768); // 2 x 64 x 512 bf16 = 128KB

  hipMemsetAsync(d_ws, 0, 32768, stream);   // zero slot ctrs + flags each launch/replay

  lstm_pers<<<dim3(256), dim3(256), 0, stream>>>(x, W, U, b, out, ws_sync, hbuf);
}